// Round 5
// baseline (30230.670 us; speedup 1.0000x reference)
//
#include <hip/hip_runtime.h>

#define T_LEN 4096
#define E_DIM 1024
#define H_DIM 512
#define NT_DIM 32
#define NG 3072          // 2 * 3H columns of gi
#define OPW 8            // h-outputs per workgroup (512 / 64)

typedef __attribute__((ext_vector_type(8))) short bf16x8;
typedef __attribute__((ext_vector_type(4))) float f32x4;
typedef unsigned long long ull;

__device__ inline unsigned short f2bf(float f) {
    unsigned int u = __float_as_uint(f);
    unsigned int r = (u + 0x7fffu + ((u >> 16) & 1u)) >> 16;
    return (unsigned short)r;
}
__device__ inline float bf2f(unsigned short u) {
    return __uint_as_float(((unsigned int)u) << 16);
}
__device__ inline ull packhs(float v, unsigned tag) {
    return (ull)__float_as_uint(v) | ((ull)tag << 32);
}

// ---------- kernel 1: embedding gather + bf16 cast  (xb[t][e]) ----------
__global__ void embed_cast(const int* __restrict__ sent, const float* __restrict__ emb,
                           unsigned short* __restrict__ xb) {
    int t = blockIdx.x;
    int row = sent[t];
    const float4* src = (const float4*)(emb + (size_t)row * E_DIM);
    ushort4* dst = (ushort4*)(xb + (size_t)t * E_DIM);
    float4 v = src[threadIdx.x];
    ushort4 o;
    o.x = f2bf(v.x); o.y = f2bf(v.y); o.z = f2bf(v.z); o.w = f2bf(v.w);
    dst[threadIdx.x] = o;
}

// ---------- kernel 2: W_ih (f then b) -> bf16, concat rows ----------
__global__ void wcast(const float* __restrict__ wf, const float* __restrict__ wb_,
                      unsigned short* __restrict__ w) {
    int r = blockIdx.x;  // 0..3071
    const float* src = (r < 1536) ? (wf + (size_t)r * E_DIM) : (wb_ + (size_t)(r - 1536) * E_DIM);
    const float4* s4 = (const float4*)src;
    ushort4* dst = (ushort4*)(w + (size_t)r * E_DIM);
    float4 v = s4[threadIdx.x];
    ushort4 o;
    o.x = f2bf(v.x); o.y = f2bf(v.y); o.z = f2bf(v.z); o.w = f2bf(v.w);
    dst[threadIdx.x] = o;
}

// ---------- kernel 3: gi = xb @ wb^T + b_ih   [4096 x 3072] -> bf16 ----------
#define LDST 40
__global__ __launch_bounds__(256) void gi_gemm(const unsigned short* __restrict__ xb,
                                               const unsigned short* __restrict__ wb,
                                               const float* __restrict__ bihf,
                                               const float* __restrict__ bihb,
                                               unsigned short* __restrict__ gi) {
    __shared__ __align__(16) unsigned short As[64 * LDST];
    __shared__ __align__(16) unsigned short Bs[64 * LDST];
    int tile_m = (blockIdx.x % 64) * 64;
    int tile_n = (blockIdx.x / 64) * 64;
    int tid = threadIdx.x;
    int lane = tid & 63, wv = tid >> 6;
    int quad = lane >> 4, r15 = lane & 15;
    int srow = tid >> 2, sseg = tid & 3;

    f32x4 acc[4] = {};
    for (int kb = 0; kb < E_DIM; kb += 32) {
        uint4 a = *(const uint4*)(xb + (size_t)(tile_m + srow) * E_DIM + kb + sseg * 8);
        uint4 b = *(const uint4*)(wb + (size_t)(tile_n + srow) * E_DIM + kb + sseg * 8);
        *(uint4*)&As[srow * LDST + sseg * 8] = a;
        *(uint4*)&Bs[srow * LDST + sseg * 8] = b;
        __syncthreads();
        bf16x8 af = *(bf16x8*)&As[(wv * 16 + r15) * LDST + quad * 8];
#pragma unroll
        for (int nt = 0; nt < 4; nt++) {
            bf16x8 bf = *(bf16x8*)&Bs[(nt * 16 + r15) * LDST + quad * 8];
            acc[nt] = __builtin_amdgcn_mfma_f32_16x16x32_bf16(af, bf, acc[nt], 0, 0, 0);
        }
        __syncthreads();
    }
#pragma unroll
    for (int nt = 0; nt < 4; nt++) {
        int gn = tile_n + nt * 16 + r15;
        float bias = (gn < 1536) ? bihf[gn] : bihb[gn - 1536];
#pragma unroll
        for (int rg = 0; rg < 4; rg++) {
            int gm = tile_m + wv * 16 + quad * 4 + rg;
            gi[(size_t)gm * NG + gn] = f2bf(acc[nt][rg] + bias);
        }
    }
}

// ---------- init: zero h-exchange planes (slow hx + fast L2 rings) ----------
// Fast rings are zeroed with agent-scope stores so the zeros are IF-visible
// (a plain store could leave dirty zero-lines in a random XCD's L2; a later
// sc0 miss from the home XCD would then fetch stale pre-init data from IF).
__global__ __launch_bounds__(256) void init_hx(ull* __restrict__ hxf, ull* __restrict__ hxb,
                                               ull* __restrict__ ff, ull* __restrict__ fb) {
    size_t stride = (size_t)gridDim.x * 256;
    size_t i = (size_t)blockIdx.x * 256 + threadIdx.x;
    for (size_t j = i; j < 2097152; j += stride) { hxf[j] = 0; hxb[j] = 0; }
    if (i < 32768) {
        __hip_atomic_store(ff + i, 0, __ATOMIC_RELAXED, __HIP_MEMORY_SCOPE_AGENT);
        __hip_atomic_store(fb + i, 0, __ATOMIC_RELAXED, __HIP_MEMORY_SCOPE_AGENT);
    }
}

// ---------- kernel 4: persistent bidirectional GRU recurrence ----------
// EXACT R0 structure (8 waves x 512thr, 64 WG/dir, wave0-only global memory,
// 2 barriers/step, 24 FMA/lane, part[] two-stage reduce — the 5890us config).
// ONLY change: h exchange goes through an XCD-local 64-row ring.
//   grid = 512 candidate blocks; HW round-robins bid%8 across the 8 XCDs.
//   bid%8==0 -> fwd (all on one XCD, shared coherent L2), bid%8==1 -> bwd,
//   others exit. Producers store {f32,tag} slots sc0 (XCD L2, ~200-300cy
//   visible) then agent-scope to hx (fallback + out_gemm). Wave0 polls the
//   ring with sc0 loads (poll period ~300cy vs ~900 via IF).
// Robust under ANY block->XCD mapping: bounded fast poll (4096 tries at s==1
// for dispatch stagger, 32/step after), per-step fallback to the proven
// agent-scope slow poll, sticky disable after 16 consecutive fast failures.
// Ring depth 64 is safe: consumer at step s needs all h(s-1), so max
// WG skew is 1 step; tags (s+1) disambiguate row reuse at distance 64.
__global__ __launch_bounds__(512) void gru_rec(
    const float* __restrict__ whhf, const float* __restrict__ bhhf,
    const float* __restrict__ whhb, const float* __restrict__ bhhb,
    const unsigned short* __restrict__ gi,
    ull* __restrict__ hxf, ull* __restrict__ hxb,
    ull* __restrict__ fastf, ull* __restrict__ fastb) {
    int x8 = blockIdx.x & 7;
    if (x8 > 1) return;                 // only the two home-XCD lanes survive
    int dir = x8;
    int g = blockIdx.x >> 3;            // 0..63
    const float* whh = dir ? whhb : whhf;
    const float* bhh = dir ? bhhb : bhhf;
    ull* hx   = dir ? hxb   : hxf;
    ull* fast = dir ? fastb : fastf;

    int tid = threadIdx.x;
    int kp = tid & 7;
    int q = tid >> 3;            // 0..63
    int kg = g * OPW + kp;
    int wave = tid >> 6;
    int lane = tid & 63;

    // persistent weights (R0 layout)
    float4 wr[2], wz[2], wn[2];
    {
        const float4* pr_ = (const float4*)(whh + (size_t)kg * H_DIM + q * 8);
        const float4* pz_ = (const float4*)(whh + (size_t)(kg + 512) * H_DIM + q * 8);
        const float4* pn_ = (const float4*)(whh + (size_t)(kg + 1024) * H_DIM + q * 8);
        wr[0] = pr_[0]; wr[1] = pr_[1];
        wz[0] = pz_[0]; wz[1] = pz_[1];
        wn[0] = pn_[0]; wn[1] = pn_[1];
    }
    float bias_r = 0.f, bias_z = 0.f, bias_n = 0.f, h_own = 0.f;
    int kg0 = g * OPW + lane;    // valid for wave==0 && lane<8
    if (wave == 0 && lane < OPW) {
        bias_r = bhh[kg0]; bias_z = bhh[kg0 + 512]; bias_n = bhh[kg0 + 1024];
    }

    __shared__ float hsh[512];
    __shared__ float part[3][8][OPW];
    hsh[tid] = 0.f;   // h_{-1} = 0
    __syncthreads();

    float gir = 0.f, giz = 0.f, gin = 0.f;
    bool fast_on = true;
    int fail_streak = 0;

    for (int s = 0; s < T_LEN; s++) {
        int row = dir ? (T_LEN - 1 - s) : s;
        if (wave == 0) {
            // gi loads issued first — in flight during the poll
            if (lane < OPW) {
                const unsigned short* gp = gi + (size_t)row * NG + dir * 1536 + kg0;
                gir = bf2f(gp[0]); giz = bf2f(gp[512]); gin = bf2f(gp[1024]);
            }
            if (s > 0) {
                int prow = dir ? (T_LEN - s) : (s - 1);
                unsigned et = (unsigned)s;
                ull v[8];
                bool got = false;
                if (fast_on) {
                    // lane's 8 slots: ring row (prow&63), slot lane+64i.
                    // byte offsets: base (lane*8), + 512*i  (fits 13-bit imm)
                    ull fa = (ull)(fast + ((size_t)(prow & 63) * H_DIM + lane));
                    int tries = (s == 1) ? 4096 : 32;
                    for (int it = 0; it < tries; ++it) {
                        asm volatile("global_load_dwordx2 %0, %1, off sc0"             : "=v"(v[0]) : "v"(fa));
                        asm volatile("global_load_dwordx2 %0, %1, off offset:512 sc0"  : "=v"(v[1]) : "v"(fa));
                        asm volatile("global_load_dwordx2 %0, %1, off offset:1024 sc0" : "=v"(v[2]) : "v"(fa));
                        asm volatile("global_load_dwordx2 %0, %1, off offset:1536 sc0" : "=v"(v[3]) : "v"(fa));
                        asm volatile("global_load_dwordx2 %0, %1, off offset:2048 sc0" : "=v"(v[4]) : "v"(fa));
                        asm volatile("global_load_dwordx2 %0, %1, off offset:2560 sc0" : "=v"(v[5]) : "v"(fa));
                        asm volatile("global_load_dwordx2 %0, %1, off offset:3072 sc0" : "=v"(v[6]) : "v"(fa));
                        asm volatile("global_load_dwordx2 %0, %1, off offset:3584 sc0" : "=v"(v[7]) : "v"(fa));
                        asm volatile("s_waitcnt vmcnt(0)" ::: "memory");
                        __builtin_amdgcn_sched_barrier(0);
                        bool ok = true;
#pragma unroll
                        for (int i = 0; i < 8; i++)
                            ok = ok && ((unsigned)(v[i] >> 32) == et);
                        if (__all(ok)) { got = true; break; }
                    }
                    if (got) fail_streak = 0;
                    else if (++fail_streak >= 16) fast_on = false;
                }
                if (!got) {
                    // R0's proven agent-scope slow poll (per-lane)
                    const ull* rowp = hx + (size_t)prow * H_DIM;
                    bool ok;
                    do {
#pragma unroll
                        for (int i = 0; i < 8; i++)
                            v[i] = __hip_atomic_load(rowp + lane + 64 * i,
                                                     __ATOMIC_RELAXED, __HIP_MEMORY_SCOPE_AGENT);
                        ok = true;
#pragma unroll
                        for (int i = 0; i < 8; i++)
                            ok = ok && ((unsigned)(v[i] >> 32) == et);
                    } while (!ok);
                }
#pragma unroll
                for (int i = 0; i < 8; i++)
                    hsh[lane + 64 * i] = __uint_as_float((unsigned)v[i]);
            }
        }
        __syncthreads();   // hsh ready

        float4 h0 = *(const float4*)&hsh[q * 8];
        float4 h1 = *(const float4*)&hsh[q * 8 + 4];
        float pr, pz, pn;
        pr  = wr[0].x * h0.x + wr[0].y * h0.y + wr[0].z * h0.z + wr[0].w * h0.w
            + wr[1].x * h1.x + wr[1].y * h1.y + wr[1].z * h1.z + wr[1].w * h1.w;
        pz  = wz[0].x * h0.x + wz[0].y * h0.y + wz[0].z * h0.z + wz[0].w * h0.w
            + wz[1].x * h1.x + wz[1].y * h1.y + wz[1].z * h1.z + wz[1].w * h1.w;
        pn  = wn[0].x * h0.x + wn[0].y * h0.y + wn[0].z * h0.z + wn[0].w * h0.w
            + wn[1].x * h1.x + wn[1].y * h1.y + wn[1].z * h1.z + wn[1].w * h1.w;
        // reduce across q within the wave (lane bits 3..5)
        pr += __shfl_xor(pr, 8);  pz += __shfl_xor(pz, 8);  pn += __shfl_xor(pn, 8);
        pr += __shfl_xor(pr, 16); pz += __shfl_xor(pz, 16); pn += __shfl_xor(pn, 16);
        pr += __shfl_xor(pr, 32); pz += __shfl_xor(pz, 32); pn += __shfl_xor(pn, 32);
        if (lane < OPW) {
            part[0][wave][lane] = pr; part[1][wave][lane] = pz; part[2][wave][lane] = pn;
        }
        __syncthreads();   // parts ready

        if (wave == 0 && lane < OPW) {
            float sr = bias_r, sz = bias_z, sn = bias_n;
#pragma unroll
            for (int w = 0; w < 8; w++) {
                sr += part[0][w][lane]; sz += part[1][w][lane]; sn += part[2][w][lane];
            }
            float rr = 1.f / (1.f + __expf(-(gir + sr)));
            float zz = 1.f / (1.f + __expf(-(giz + sz)));
            float a = gin + rr * sn;
            a = fminf(20.f, fmaxf(-20.f, a));
            float e = __expf(-2.f * a);
            float nn = (1.f - e) / (1.f + e);
            float hnew = (1.f - zz) * nn + zz * h_own;
            h_own = hnew;
            ull pv = packhs(hnew, (unsigned)(s + 1));
            // fast store first (critical path: XCD-local L2), then IF-scope
            ull faddr = (ull)(fast + ((size_t)(row & 63) * H_DIM + kg0));
            asm volatile("global_store_dwordx2 %0, %1, off sc0" :: "v"(faddr), "v"(pv) : "memory");
            __hip_atomic_store(hx + (size_t)row * H_DIM + kg0, pv,
                               __ATOMIC_RELAXED, __HIP_MEMORY_SCOPE_AGENT);
        }
        // hsh for next step is rewritten only by wave 0 AFTER it passes the
        // parts barrier; all other waves' hsh reads for this step precede it.
    }
}

// ---------- kernel 5: out = [hf|hb] @ W_out^T   [4096 x 32] ----------
__global__ __launch_bounds__(256) void out_gemm(const ull* __restrict__ hxf,
                                                const ull* __restrict__ hxb,
                                                const float* __restrict__ wout,
                                                float* __restrict__ out) {
    __shared__ __align__(16) float ls[8][1028];
    int t0 = blockIdx.x * 8;
    int tid = threadIdx.x;
#pragma unroll
    for (int i = 0; i < 8; i++) {
        int col = tid * 4;   // 0..1020
        const ull* src = (col < 512) ? (hxf + (size_t)(t0 + i) * H_DIM + col)
                                     : (hxb + (size_t)(t0 + i) * H_DIM + (col - 512));
        ull s0 = src[0], s1 = src[1], s2 = src[2], s3 = src[3];
        ls[i][col + 0] = __uint_as_float((unsigned)s0);
        ls[i][col + 1] = __uint_as_float((unsigned)s1);
        ls[i][col + 2] = __uint_as_float((unsigned)s2);
        ls[i][col + 3] = __uint_as_float((unsigned)s3);
    }
    __syncthreads();
    int r8 = tid >> 5, gg = tid & 31;
    const float4* wp = (const float4*)(wout + (size_t)gg * 1024);
    float sum = 0.f;
#pragma unroll 8
    for (int j = 0; j < 256; j++) {
        float4 w = wp[j];
        float4 h = *(const float4*)&ls[r8][j * 4];
        sum += w.x * h.x + w.y * h.y + w.z * h.z + w.w * h.w;
    }
    out[(size_t)(t0 + r8) * NT_DIM + gg] = sum;
}

extern "C" void kernel_launch(void* const* d_in, const int* in_sizes, int n_in,
                              void* d_out, int out_size, void* d_ws, size_t ws_size,
                              hipStream_t stream) {
    const int*   sent = (const int*)d_in[0];
    const float* emb  = (const float*)d_in[1];
    const float* wihf = (const float*)d_in[2];
    const float* whhf = (const float*)d_in[3];
    const float* bihf = (const float*)d_in[4];
    const float* bhhf = (const float*)d_in[5];
    const float* wihb = (const float*)d_in[6];
    const float* whhb = (const float*)d_in[7];
    const float* bihb = (const float*)d_in[8];
    const float* bhhb = (const float*)d_in[9];
    const float* wout = (const float*)d_in[10];

    char* ws = (char*)d_ws;
    unsigned short* gi  = (unsigned short*)(ws);              // 4096*3072*2 = 25165824
    unsigned short* xb  = (unsigned short*)(ws + 25165824);   // 4096*1024*2 =  8388608
    unsigned short* wb  = (unsigned short*)(ws + 33554432);   // 3072*1024*2 =  6291456
    ull*            hxf = (ull*)(ws + 39845888);              // 4096*512*8  = 16777216
    ull*            hxb = (ull*)(ws + 56623104);              // 16777216 (total 73400320)
    // fast L2 rings (64 rows x 512 slots x 8B = 256KB each) reuse the xb/wb
    // regions, which are dead after gi_gemm completes (stream-ordered).
    ull*            fastf = (ull*)(ws + 25165824);
    ull*            fastb = (ull*)(ws + 33554432);
    float*          out = (float*)d_out;

    embed_cast<<<T_LEN, 256, 0, stream>>>(sent, emb, xb);
    wcast<<<NG, 256, 0, stream>>>(wihf, wihb, wb);
    gi_gemm<<<64 * 48, 256, 0, stream>>>(xb, wb, bihf, bihb, gi);
    init_hx<<<2048, 256, 0, stream>>>(hxf, hxb, fastf, fastb);
    gru_rec<<<512, 512, 0, stream>>>(whhf, bhhf, whhb, bhhb, gi, hxf, hxb, fastf, fastb);
    out_gemm<<<T_LEN / 8, 256, 0, stream>>>(hxf, hxb, wout, out);
}